// Round 12
// baseline (59.346 us; speedup 1.0000x reference)
//
#include <hip/hip_runtime.h>
#include <hip/hip_fp16.h>

typedef __attribute__((ext_vector_type(8))) _Float16 half8;
typedef __attribute__((ext_vector_type(4))) float f32x4;

union U2H2 { unsigned int u; __half2 h; };

static __device__ __forceinline__ unsigned int pack2h(float a, float b) {
    U2H2 c; c.h = __floats2half2_rn(a, b); return c.u;
}
static __device__ __forceinline__ __half2 u_as_h2(unsigned int u) {
    U2H2 c; c.u = u; return c.h;
}
static __device__ __forceinline__ __half2 hi16(unsigned int u) {
    return u_as_h2(__builtin_amdgcn_perm(u, u, 0x03020302u));
}

// fence LDS + barrier WITHOUT draining vmcnt (prefetched loads stay in flight)
#define LDS_BARRIER()                                                \
    do {                                                             \
        asm volatile("s_waitcnt lgkmcnt(0)" ::: "memory");           \
        __builtin_amdgcn_s_barrier();                                \
        __builtin_amdgcn_sched_barrier(0);                           \
    } while (0)

// Prep: blocks [0,nT): transpose x -> xth [N][2][32] fp16 (b-halves share a
// 128B line); blocks [nT,nT+26): repack W -> Wrh[k][o][c] fp16 (k=25 zeros).
__global__ __launch_bounds__(256) void prep_all(const float* __restrict__ x,
                                                const float* __restrict__ W,
                                                unsigned short* __restrict__ xth,
                                                unsigned short* __restrict__ Wrh,
                                                int N, int nT) {
    int bid = blockIdx.x, tid = threadIdx.x;
    if (bid >= nT) {
        int k = bid - nT;  // 0..25
#pragma unroll
        for (int it = 0; it < 8; ++it) {
            int r = tid + 256 * it;          // 0..2047 = o*32+c
            int o = r >> 5, c = r & 31;
            float v = (k < 25) ? W[o * 800 + c * 25 + k] : 0.f;
            __half h = __float2half(v);
            Wrh[k * 2048 + r] = *reinterpret_cast<unsigned short*>(&h);
        }
        return;
    }
    __shared__ float t[2][32][65];
    int n0 = bid * 64;
#pragma unroll
    for (int i = 0; i < 16; ++i) {
        int e = tid + 256 * i;               // [2][32][64]
        int b = e >> 11, c = (e >> 6) & 31, nl = e & 63;
        int n = n0 + nl;
        t[b][c][nl] = (n < N) ? x[(size_t)(b * 32 + c) * N + n] : 0.f;
    }
    __syncthreads();
    int nl = tid >> 2, q = tid & 3, n = n0 + nl;
    if (n < N) {
#pragma unroll
        for (int b = 0; b < 2; ++b) {
            uint4 p;
            p.x = pack2h(t[b][q * 8 + 0][nl], t[b][q * 8 + 1][nl]);
            p.y = pack2h(t[b][q * 8 + 2][nl], t[b][q * 8 + 3][nl]);
            p.z = pack2h(t[b][q * 8 + 4][nl], t[b][q * 8 + 5][nl]);
            p.w = pack2h(t[b][q * 8 + 6][nl], t[b][q * 8 + 7][nl]);
            *reinterpret_cast<uint4*>(xth + ((size_t)n * 64 + b * 32 + q * 8)) = p;
        }
    }
}

// Fused gather + einsum + MFMA + bias. 32-n tile, 2 k-slices per barrier
// period (13 uniform periods over k=0..25, slice 25 = zeros). 128B LDS rows
// with slice-interleaved 16B slots, slot' = ((q<<1)|ks) ^ (row&7).
__global__ __launch_bounds__(256) void fused_main(
    const unsigned short* __restrict__ xth,  // [N][2][32] fp16
    const unsigned short* __restrict__ Wrh,  // [26][64][32] fp16
    const float* __restrict__ bias,          // [64]
    const int* __restrict__ nidx,            // [N][25][3]
    const float* __restrict__ nw,            // [N][25][3]
    float* __restrict__ out,                 // [2][64][N] fp32
    int N)
{
    __shared__ unsigned int idxw[32 * 26 * 4];           // [nl][26][4]: j | half(w)<<16
    __shared__ __align__(16) unsigned char sA[2][8192];  // dbuf: 64 rows x 128B (2 slices)
    __shared__ __align__(16) unsigned char sB[2][8192];  // dbuf: 64 o-rows x 128B

    const int tid = threadIdx.x;
    const int n0 = blockIdx.x * 32;

    // ---- zero idx table (pads + slice 25), then fill slices 0..24 ----
#pragma unroll
    for (int it = 0; it < 13; ++it) {
        int e = tid + 256 * it;
        if (e < 3328) idxw[e] = 0u;
    }
    __syncthreads();
#pragma unroll
    for (int it = 0; it < 10; ++it) {
        int e = tid + 256 * it;
        if (e < 2400) {
            int nl = e / 75, r = e - nl * 75;
            int kk = r / 3, t = r - kk * 3;
            int n = n0 + nl;
            unsigned int u = 0;
            if (n < N) {
                size_t s = (size_t)n0 * 75 + e;
                int j = nidx[s];
                __half hw = __float2half(nw[s]);
                u = (unsigned int)j |
                    ((unsigned int)*reinterpret_cast<unsigned short*>(&hw) << 16);
            }
            idxw[nl * 104 + kk * 4 + t] = u;
        }
    }
    __syncthreads();

    const int nl = tid >> 3;                   // n-row 0..31 this thread gathers
    const int p8 = tid & 7;                    // 16B slice of the 128B pair-line
    const int grow = (p8 >> 2) * 32 + nl;      // sA row = b*32 + nl
    const int gq = p8 & 3;                     // c-quad within the 64B half
    // sA write offsets, slice-interleaved slots: slot' = ((q<<1)|ks)^(row&7)
    const int wr_k0 = grow * 128 + ((((gq << 1) | 0) ^ (grow & 7)) << 4);
    const int wr_k1 = wr_k0 ^ 16;

    // sB: thread t -> o-row t>>2, c-quad t&3
    const int borow = tid >> 2, bq = tid & 3;
    const int sbo_k0 = borow * 128 + ((((bq << 1) | 0) ^ (borow & 7)) << 4);
    const int sbo_k1 = sbo_k0 ^ 16;
    const int gbo = borow * 32 + bq * 8;       // Wrh halfword offset per slice

    const int l = tid & 63, wv = tid >> 6, c16 = l & 15, g = l >> 4;
    const int arow = 16 * wv + c16;
    const int rd_a0 = arow * 128 + ((((g << 1) | 0) ^ (arow & 7)) << 4);
    const int rd_a1 = rd_a0 ^ 16;
    const int bf_b0 = c16 * 128 + ((((g << 1) | 0) ^ (c16 & 7)) << 4);
    const int bf_b1 = bf_b0 ^ 16;

    const unsigned short* xg = xth + p8 * 8;   // + j*64 per gather
    const unsigned int* iprow = &idxw[nl * 104];

    unsigned int ruA[6], ruB[6];
    uint4 rgA[6], rgB[6];
    uint4 rBv0, rBv1;

    f32x4 acc[4];
#pragma unroll
    for (int ot = 0; ot < 4; ++ot) acc[ot] = (f32x4){0.f, 0.f, 0.f, 0.f};

    // ---- prologue: B(period 0); idx+gathers for periods 0,1 (slices 0..3) ----
    rBv0 = *reinterpret_cast<const uint4*>(Wrh + gbo);
    rBv1 = *reinterpret_cast<const uint4*>(Wrh + 2048 + gbo);
    {
        uint4 i0 = *reinterpret_cast<const uint4*>(iprow + 0);
        uint4 i1 = *reinterpret_cast<const uint4*>(iprow + 4);
        uint4 i2 = *reinterpret_cast<const uint4*>(iprow + 8);
        uint4 i3 = *reinterpret_cast<const uint4*>(iprow + 12);
        ruA[0] = i0.x; ruA[1] = i0.y; ruA[2] = i0.z;
        ruA[3] = i1.x; ruA[4] = i1.y; ruA[5] = i1.z;
        ruB[0] = i2.x; ruB[1] = i2.y; ruB[2] = i2.z;
        ruB[3] = i3.x; ruB[4] = i3.y; ruB[5] = i3.z;
    }
#pragma unroll
    for (int t = 0; t < 6; ++t)
        rgA[t] = *reinterpret_cast<const uint4*>(xg + (ruA[t] & 0xffffu) * 64);
#pragma unroll
    for (int t = 0; t < 6; ++t)
        rgB[t] = *reinterpret_cast<const uint4*>(xg + (ruB[t] & 0xffffu) * 64);

#define HFMA_STORE(U0, U1, U2, V0, V1, V2, OFF)                                    \
    do {                                                                           \
        __half2 w0 = hi16(U0), w1 = hi16(U1), w2 = hi16(U2);                       \
        uint4 pk; U2H2 c;                                                          \
        c.h = __hfma2(u_as_h2((V0).x), w0,                                         \
              __hfma2(u_as_h2((V1).x), w1, __hmul2(u_as_h2((V2).x), w2)));         \
        pk.x = c.u;                                                                \
        c.h = __hfma2(u_as_h2((V0).y), w0,                                         \
              __hfma2(u_as_h2((V1).y), w1, __hmul2(u_as_h2((V2).y), w2)));         \
        pk.y = c.u;                                                                \
        c.h = __hfma2(u_as_h2((V0).z), w0,                                         \
              __hfma2(u_as_h2((V1).z), w1, __hmul2(u_as_h2((V2).z), w2)));         \
        pk.z = c.u;                                                                \
        c.h = __hfma2(u_as_h2((V0).w), w0,                                         \
              __hfma2(u_as_h2((V1).w), w1, __hmul2(u_as_h2((V2).w), w2)));         \
        pk.w = c.u;                                                                \
        *reinterpret_cast<uint4*>(OFF) = pk;                                       \
    } while (0)

#define PERIOD(P, RG, RU)                                                          \
    do {                                                                           \
        const int pb = (P) & 1;                                                    \
        /* stage B pair; refill B for period P+1 */                                \
        *reinterpret_cast<uint4*>(&sB[pb][sbo_k0]) = rBv0;                         \
        *reinterpret_cast<uint4*>(&sB[pb][sbo_k1]) = rBv1;                         \
        {                                                                          \
            int kb0 = 2 * (P) + 2; kb0 = kb0 > 25 ? 25 : kb0;                      \
            int kb1 = 2 * (P) + 3; kb1 = kb1 > 25 ? 25 : kb1;                      \
            rBv0 = *reinterpret_cast<const uint4*>(Wrh + kb0 * 2048 + gbo);        \
            rBv1 = *reinterpret_cast<const uint4*>(Wrh + kb1 * 2048 + gbo);        \
        }                                                                          \
        /* weighted fp16 sums -> sA (both slices) */                               \
        HFMA_STORE(RU[0], RU[1], RU[2], RG[0], RG[1], RG[2], &sA[pb][wr_k0]);      \
        HFMA_STORE(RU[3], RU[4], RU[5], RG[3], RG[4], RG[5], &sA[pb][wr_k1]);      \
        /* idx prefetch for period P+2 (drained at the barrier) */                 \
        uint4 niq0, niq1;                                                          \
        {                                                                          \
            int ka = 2 * (P) + 4; ka = ka > 25 ? 25 : ka;                          \
            int kb = 2 * (P) + 5; kb = kb > 25 ? 25 : kb;                          \
            niq0 = *reinterpret_cast<const uint4*>(iprow + ka * 4);                \
            niq1 = *reinterpret_cast<const uint4*>(iprow + kb * 4);                \
        }                                                                          \
        LDS_BARRIER();                                                             \
        /* issue gathers for period P+2 (vmem stays in flight across periods) */   \
        RU[0] = niq0.x; RU[1] = niq0.y; RU[2] = niq0.z;                            \
        RU[3] = niq1.x; RU[4] = niq1.y; RU[5] = niq1.z;                            \
        RG[0] = *reinterpret_cast<const uint4*>(xg + (RU[0] & 0xffffu) * 64);      \
        RG[1] = *reinterpret_cast<const uint4*>(xg + (RU[1] & 0xffffu) * 64);      \
        RG[2] = *reinterpret_cast<const uint4*>(xg + (RU[2] & 0xffffu) * 64);      \
        RG[3] = *reinterpret_cast<const uint4*>(xg + (RU[3] & 0xffffu) * 64);      \
        RG[4] = *reinterpret_cast<const uint4*>(xg + (RU[4] & 0xffffu) * 64);      \
        RG[5] = *reinterpret_cast<const uint4*>(xg + (RU[5] & 0xffffu) * 64);      \
        /* MFMA: 2 slices x 4 o-tiles */                                           \
        {                                                                          \
            half8 af0 = *reinterpret_cast<const half8*>(&sA[pb][rd_a0]);           \
            half8 af1 = *reinterpret_cast<const half8*>(&sA[pb][rd_a1]);           \
            __builtin_amdgcn_s_setprio(1);                                         \
            _Pragma("unroll")                                                      \
            for (int ot = 0; ot < 4; ++ot) {                                       \
                half8 bf0 = *reinterpret_cast<const half8*>(                       \
                    &sB[pb][bf_b0 + ot * 2048]);                                   \
                acc[ot] = __builtin_amdgcn_mfma_f32_16x16x32_f16(af0, bf0,         \
                                                                 acc[ot], 0, 0, 0);\
            }                                                                      \
            _Pragma("unroll")                                                      \
            for (int ot = 0; ot < 4; ++ot) {                                       \
                half8 bf1 = *reinterpret_cast<const half8*>(                       \
                    &sB[pb][bf_b1 + ot * 2048]);                                   \
                acc[ot] = __builtin_amdgcn_mfma_f32_16x16x32_f16(af1, bf1,         \
                                                                 acc[ot], 0, 0, 0);\
            }                                                                      \
            __builtin_amdgcn_s_setprio(0);                                         \
        }                                                                          \
    } while (0)

    PERIOD(0, rgA, ruA);
    PERIOD(1, rgB, ruB);
    PERIOD(2, rgA, ruA);
    PERIOD(3, rgB, ruB);
    PERIOD(4, rgA, ruA);
    PERIOD(5, rgB, ruB);
    PERIOD(6, rgA, ruA);
    PERIOD(7, rgB, ruB);
    PERIOD(8, rgA, ruA);
    PERIOD(9, rgB, ruB);
    PERIOD(10, rgA, ruA);
    PERIOD(11, rgB, ruB);
    PERIOD(12, rgA, ruA);

#undef PERIOD
#undef HFMA_STORE

    // ---- epilogue: bias + store (D: o = ot*16+c16, row = 16wv+4g+i) ----
#pragma unroll
    for (int ot = 0; ot < 4; ++ot) {
        int o = ot * 16 + c16;
        float bv = bias[o];
#pragma unroll
        for (int i = 0; i < 4; ++i) {
            int mrow = 16 * wv + 4 * g + i;
            int b = mrow >> 5, nn = n0 + (mrow & 31);
            if (nn < N) out[((size_t)b * 64 + o) * N + nn] = acc[ot][i] + bv;
        }
    }
}

extern "C" void kernel_launch(void* const* d_in, const int* in_sizes, int n_in,
                              void* d_out, int out_size, void* d_ws, size_t ws_size,
                              hipStream_t stream) {
    const float* x    = (const float*)d_in[0];   // (2,32,N)
    const float* nw   = (const float*)d_in[1];   // (N,25,3)
    const float* W    = (const float*)d_in[2];   // (64,800)
    const float* bias = (const float*)d_in[3];   // (64,)
    const int*   nidx = (const int*)d_in[4];     // (N,25,3)
    float* out = (float*)d_out;

    int N = in_sizes[0] / 64;  // B*C = 64

    unsigned short* xth = (unsigned short*)d_ws;      // [N][2][32] fp16
    unsigned short* Wrh = xth + (size_t)N * 64;       // [26][64][32] fp16

    int nT = (N + 63) / 64;
    prep_all<<<nT + 26, 256, 0, stream>>>(x, W, xth, Wrh, N, nT);

    fused_main<<<(N + 31) / 32, 256, 0, stream>>>(xth, Wrh, bias, nidx, nw, out, N);
}